// Round 10
// baseline (67.987 us; speedup 1.0000x reference)
//
#include <hip/hip_runtime.h>
#include <hip/hip_bf16.h>

#define NPTS 2048      // N == M == 2048
#define QMIX 8
#define LATD 64
#define NIT  4         // i-tiles (16 rows each) per pair block

typedef float f32x4 __attribute__((ext_vector_type(4)));
typedef short short8 __attribute__((ext_vector_type(8)));   // 8 bf16 (4 VGPRs)

__device__ __forceinline__ float softplus_f(float x) {
    return fmaxf(x, 0.0f) + log1pf(expf(-fabsf(x)));
}
__device__ __forceinline__ float selu_f(float z) {
    const float sc = 1.0507009873554805f;
    const float sa = 1.7580993408473766f;
    return (z > 0.0f) ? sc * z : sa * expm1f(z);
}
__device__ __forceinline__ ushort bfrn(float v) {   // round-to-nearest bf16
    unsigned b = __float_as_uint(v);
    return (ushort)((b + 0x7fffu + ((b >> 16) & 1u)) >> 16);
}
__device__ __forceinline__ void split_bf16(float v, ushort& h, ushort& l) {
    unsigned b  = __float_as_uint(v);
    unsigned hb = b & 0xffff0000u;          // truncated hi
    h = (ushort)(hb >> 16);
    l = bfrn(v - __uint_as_float(hb));      // rounded residual
}

// Slot layout per (point, q), 32 bf16 slots (hi + lo arrays):
//  X rows: [0..9]=coef, [10..19]=monomials, [20..31]=0
//  Y rows: [0..9]=monomials, [10..19]=coef, [20..31]=0
//  coef      = EF*[A00,A11,A22,2A01,2A02,2A12, -2Ax0,-2Ax1,-2Ax2, pAp]
//  monomials = [p0^2,p1^2,p2^2,p0p1,p0p2,p1p2, p0,p1,p2, 1]
//  => dot(Xrow[i,q], Yrow[j,q]) = EF*(qx+qy) = u;  exp(-sqrt5*r)=exp2(-u)
//  CTX/CTY[pt*8+q] = packed bf16 {w*cos, w*sin}  (K=2 cosine dot)
__global__ __launch_bounds__(640) void feat_kernel(
    const float* __restrict__ xin, const float* __restrict__ yin,
    const float* __restrict__ W1, const float* __restrict__ b1,
    const float* __restrict__ Ww, const float* __restrict__ bw,
    const float* __restrict__ Wf, const float* __restrict__ bf,
    const float* __restrict__ Ws, const float* __restrict__ bs,
    ushort* __restrict__ AXH, ushort* __restrict__ AXL,
    ushort* __restrict__ BYH, ushort* __restrict__ BYL,
    uint* __restrict__ CTX, uint* __restrict__ CTY)
{
    __shared__ float hsh[8][LATD + 4];
    __shared__ float raw[8][80];
    const int t = threadIdx.x;

    // phase 1: hidden layer
    if (t < 512) {
        const int pl = t & 7, l = t >> 3;
        const int g = blockIdx.x * 8 + pl;
        const bool isx = (g < NPTS);
        const float* pts = isx ? (xin + 3 * g) : (yin + 3 * (g - NPTS));
        const float z = fmaf(W1[l * 3 + 0], pts[0],
                        fmaf(W1[l * 3 + 1], pts[1],
                        fmaf(W1[l * 3 + 2], pts[2], b1[l])));
        hsh[pl][l] = selu_f(z);
    }
    __syncthreads();

    // phase 2: head dots
    {
        const int o  = t >> 3;
        const int pl = t & 7;
        const int q  = o / 10;
        const int e  = o % 10;
        const float* row;
        float acc;
        if (e == 0)      { row = Ww + q * LATD;                 acc = bw[q]; }
        else if (e <= 3) { row = Wf + (q * 3 + (e - 1)) * LATD; acc = bf[q * 3 + (e - 1)]; }
        else             { row = Ws + (q * 6 + (e - 4)) * LATD; acc = bs[q * 6 + (e - 4)]; }
#pragma unroll
        for (int l4 = 0; l4 < LATD / 4; ++l4) {
            const float4 rv = reinterpret_cast<const float4*>(row)[l4];
            const float4 hv = *reinterpret_cast<const float4*>(&hsh[pl][l4 * 4]);
            acc = fmaf(rv.x, hv.x, acc);
            acc = fmaf(rv.y, hv.y, acc);
            acc = fmaf(rv.z, hv.z, acc);
            acc = fmaf(rv.w, hv.w, acc);
        }
        raw[pl][o] = softplus_f(acc);
    }
    __syncthreads();

    // phase 3: expand quadratic form and emit split-bf16 rows
    if (t < 64) {
        const int pl2 = t >> 3, q2 = t & 7;
        const int g2  = blockIdx.x * 8 + pl2;
        const bool isx2 = (g2 < NPTS);
        const float* pts2 = isx2 ? (xin + 3 * g2) : (yin + 3 * (g2 - NPTS));
        const float c0 = pts2[0], c1 = pts2[1], c2 = pts2[2];
        const float* rr = raw[pl2] + q2 * 10;
        const float w  = rr[0];
        const float f0 = rr[1], f1 = rr[2], f2 = rr[3];
        const float s0 = rr[4], s1 = rr[5], s2 = rr[6];
        const float s3 = rr[7], s4 = rr[8], s5 = rr[9];

        // A = L L^T
        const float A00 = s0 * s0;
        const float A01 = s0 * s1;
        const float A02 = s0 * s3;
        const float A11 = fmaf(s1, s1, s2 * s2);
        const float A12 = fmaf(s1, s3, s2 * s4);
        const float A22 = fmaf(s3, s3, fmaf(s4, s4, s5 * s5));
        const float Ax0 = fmaf(A00, c0, fmaf(A01, c1, A02 * c2));
        const float Ax1 = fmaf(A01, c0, fmaf(A11, c1, A12 * c2));
        const float Ax2 = fmaf(A02, c0, fmaf(A12, c1, A22 * c2));
        const float pAp = fmaf(c0, Ax0, fmaf(c1, Ax1, c2 * Ax2));
        const float ph  = fmaf(f0, c0, fmaf(f1, c1, f2 * c2));
        float sn, cs;
        sincosf(6.283185307179586477f * ph, &sn, &cs);

        const float EF = 3.2259751249059600974f;   // sqrt(5)*log2(e)
        const float cf[10] = { EF * A00, EF * A11, EF * A22,
                               2.0f * EF * A01, 2.0f * EF * A02, 2.0f * EF * A12,
                               -2.0f * EF * Ax0, -2.0f * EF * Ax1, -2.0f * EF * Ax2,
                               EF * pAp };
        const float pv[10] = { c0 * c0, c1 * c1, c2 * c2,
                               c0 * c1, c0 * c2, c1 * c2,
                               c0, c1, c2, 1.0f };
        float slots[20];
#pragma unroll
        for (int k = 0; k < 10; ++k) {
            slots[k]      = isx2 ? cf[k] : pv[k];
            slots[10 + k] = isx2 ? pv[k] : cf[k];
        }
        ushort H[32], L[32];
#pragma unroll
        for (int k = 0; k < 32; ++k) { H[k] = 0; L[k] = 0; }
#pragma unroll
        for (int k = 0; k < 20; ++k) split_bf16(slots[k], H[k], L[k]);

        const int pi = isx2 ? g2 : (g2 - NPTS);
        ushort* dh = (isx2 ? AXH : BYH) + ((size_t)pi * 8 + q2) * 32;
        ushort* dl = (isx2 ? AXL : BYL) + ((size_t)pi * 8 + q2) * 32;
#pragma unroll
        for (int m = 0; m < 16; ++m) {
            ((uint*)dh)[m] = (uint)H[2 * m] | ((uint)H[2 * m + 1] << 16);
            ((uint*)dl)[m] = (uint)L[2 * m] | ((uint)L[2 * m + 1] << 16);
        }
        uint* ct = isx2 ? CTX : CTY;
        ct[(size_t)pi * 8 + q2] = (uint)bfrn(w * cs) | ((uint)bfrn(w * sn) << 16);
    }
}

// Pair kernel: wave = one 16x16 output tile (j-tile fixed per wave, i-tiles
// looped). u via 3 split-bf16 MFMAs, ct via 1 K=2 MFMA; epilogue does
// poly*exp2(-u)*ct per element. A-tiles staged in XOR-swizzled LDS
// (512B row stride would be a 16-way bank conflict otherwise).
__global__ __launch_bounds__(256, 4) void pair_kernel(
    const ushort* __restrict__ AXH, const ushort* __restrict__ AXL,
    const uint*  __restrict__ CTX,
    const ushort* __restrict__ BYH, const ushort* __restrict__ BYL,
    const uint*  __restrict__ CTY, float* __restrict__ out)
{
    __shared__ ushort sAH[16 * 256];   // 8 KB (swizzled)
    __shared__ ushort sAL[16 * 256];   // 8 KB (swizzled)
    __shared__ uint   sCT[16 * 9];     // stride-9 padded
    const int t   = threadIdx.x;
    const int wv  = t >> 6, ln = t & 63;
    const int col = ln & 15, kb = ln >> 4;
    const int j0  = blockIdx.x * 64 + wv * 16;
    const int it0 = blockIdx.y * NIT;

    // resident B-side fragments (j-tile fixed for the whole block)
    short8 Bh[8], Bl[8], Bc[8];
    {
        const ushort* bh = BYH + (size_t)(j0 + col) * 256 + kb * 8;
        const ushort* bl = BYL + (size_t)(j0 + col) * 256 + kb * 8;
#pragma unroll
        for (int q = 0; q < 8; ++q) {
            Bh[q] = *reinterpret_cast<const short8*>(bh + q * 32);
            Bl[q] = *reinterpret_cast<const short8*>(bl + q * 32);
            const uint cv = (kb == 2) ? CTY[(size_t)(j0 + col) * 8 + q] : 0u;
            short8 bc = {0, 0, 0, 0, (short)(cv & 0xffffu), (short)(cv >> 16), 0, 0};
            Bc[q] = bc;
        }
    }
    const float P1 = 0.69314718055994530942f;   // ln2
    const float P2 = 0.16013630893549922444f;   // ln2^2/3

    for (int it = 0; it < NIT; ++it) {
        const int i0 = (it0 + it) * 16;
        if (it) __syncthreads();    // prior tile's reads done before overwrite
        {
            const uint4* srcH = reinterpret_cast<const uint4*>(AXH + (size_t)i0 * 256);
            const uint4* srcL = reinterpret_cast<const uint4*>(AXL + (size_t)i0 * 256);
#pragma unroll
            for (int u = 0; u < 2; ++u) {
                const int s   = t + u * 256;          // 0..511 16B-chunks
                const int row = s >> 5, sl = s & 31;
                const int ds  = row * 32 + (sl ^ row);  // XOR swizzle
                reinterpret_cast<uint4*>(sAH)[ds] = srcH[s];
                reinterpret_cast<uint4*>(sAL)[ds] = srcL[s];
            }
            if (t < 128) sCT[(t >> 3) * 9 + (t & 7)] =
                CTX[(size_t)(i0 + (t >> 3)) * 8 + (t & 7)];
        }
        __syncthreads();

        f32x4 kacc = {0.f, 0.f, 0.f, 0.f};
#pragma unroll
        for (int q = 0; q < 8; ++q) {
            // swizzled read: logical 16B-chunk (q*4+kb) of row col
            const int ro = col * 256 + (((q * 4 + kb) ^ col) << 3);
            const short8 Ah = *reinterpret_cast<const short8*>(sAH + ro);
            const short8 Al = *reinterpret_cast<const short8*>(sAL + ro);
            const f32x4 z = {0.f, 0.f, 0.f, 0.f};
            f32x4 au = __builtin_amdgcn_mfma_f32_16x16x32_bf16(Ah, Bh[q], z, 0, 0, 0);
            au = __builtin_amdgcn_mfma_f32_16x16x32_bf16(Al, Bh[q], au, 0, 0, 0);
            au = __builtin_amdgcn_mfma_f32_16x16x32_bf16(Ah, Bl[q], au, 0, 0, 0);
            const uint av = (kb == 2) ? sCT[col * 9 + q] : 0u;
            short8 Ac = {0, 0, 0, 0, (short)(av & 0xffffu), (short)(av >> 16), 0, 0};
            const f32x4 ac = __builtin_amdgcn_mfma_f32_16x16x32_bf16(Ac, Bc[q], z, 0, 0, 0);
#pragma unroll
            for (int e = 0; e < 4; ++e) {
                const float u  = au[e];
                const float po = fmaf(u, fmaf(u, P2, P1), 1.0f);
                const float ex = __builtin_amdgcn_exp2f(-u);
                kacc[e] = fmaf(po * ex, ac[e], kacc[e]);
            }
        }
        // D layout: row = kb*4+e, col = lane&15  [m89-verified]
#pragma unroll
        for (int e = 0; e < 4; ++e)
            out[(size_t)(i0 + kb * 4 + e) * NPTS + j0 + col] = kacc[e];
    }
}

extern "C" void kernel_launch(void* const* d_in, const int* in_sizes, int n_in,
                              void* d_out, int out_size, void* d_ws, size_t ws_size,
                              hipStream_t stream) {
    const float* x  = (const float*)d_in[0];
    const float* y  = (const float*)d_in[1];
    const float* W1 = (const float*)d_in[2];
    const float* b1 = (const float*)d_in[3];
    const float* Ww = (const float*)d_in[4];
    const float* bw = (const float*)d_in[5];
    const float* Wf = (const float*)d_in[6];
    const float* bf = (const float*)d_in[7];
    const float* Ws = (const float*)d_in[8];
    const float* bs = (const float*)d_in[9];
    float* out = (float*)d_out;

    ushort* AXH = (ushort*)d_ws;                 // [2048][8][32] bf16 hi
    ushort* AXL = AXH + (size_t)NPTS * 256;      // lo
    ushort* BYH = AXL + (size_t)NPTS * 256;
    ushort* BYL = BYH + (size_t)NPTS * 256;
    uint*   CTX = (uint*)(BYL + (size_t)NPTS * 256);  // [2048][8] packed {wc,ws}
    uint*   CTY = CTX + (size_t)NPTS * 8;

    feat_kernel<<<dim3((2 * NPTS) / 8), dim3(640), 0, stream>>>(
        x, y, W1, b1, Ww, bw, Wf, bf, Ws, bs, AXH, AXL, BYH, BYL, CTX, CTY);

    // (32 j-blocks of 64 cols, 32 i-strips of NIT*16 rows)
    pair_kernel<<<dim3(NPTS / 64, NPTS / (NIT * 16)), dim3(256), 0, stream>>>(
        AXH, AXL, CTX, BYH, BYL, CTY, out);
}

// Round 11
// 53.079 us; speedup vs baseline: 1.2809x; 1.2809x over previous
//
#include <hip/hip_runtime.h>
#include <hip/hip_bf16.h>

#define NPTS 2048      // N == M == 2048
#define QMIX 8
#define LATD 64
#define NIT  4         // i-tiles (16 rows each) per pair block

typedef float f32x4 __attribute__((ext_vector_type(4)));
typedef short short8 __attribute__((ext_vector_type(8)));   // 8 bf16 (4 VGPRs)

__device__ __forceinline__ float softplus_f(float x) {
    return fmaxf(x, 0.0f) + log1pf(expf(-fabsf(x)));
}
__device__ __forceinline__ float selu_f(float z) {
    const float sc = 1.0507009873554805f;
    const float sa = 1.7580993408473766f;
    return (z > 0.0f) ? sc * z : sa * expm1f(z);
}
__device__ __forceinline__ ushort bfrn(float v) {   // round-to-nearest bf16
    unsigned b = __float_as_uint(v);
    return (ushort)((b + 0x7fffu + ((b >> 16) & 1u)) >> 16);
}
__device__ __forceinline__ void split_bf16(float v, ushort& h, ushort& l) {
    unsigned b  = __float_as_uint(v);
    unsigned hb = b & 0xffff0000u;          // truncated hi
    h = (ushort)(hb >> 16);
    l = bfrn(v - __uint_as_float(hb));      // rounded residual
}
__device__ __forceinline__ short8 ct_frag(uint av) {
    // nonzero bf16 pair at elements 4,5 (k-slots 20,21 for the kb==2 group)
    int4 r; r.x = 0; r.y = 0; r.z = (int)av; r.w = 0;
    return __builtin_bit_cast(short8, r);
}

// Slot layout per (point, q), 32 bf16 slots (hi + lo arrays):
//  X rows: [0..9]=coef, [10..19]=monomials, [20..31]=0
//  Y rows: [0..9]=monomials, [10..19]=coef, [20..31]=0
//  coef      = EF*[A00,A11,A22,2A01,2A02,2A12, -2Ax0,-2Ax1,-2Ax2, pAp]
//  monomials = [p0^2,p1^2,p2^2,p0p1,p0p2,p1p2, p0,p1,p2, 1]
//  => dot(Xrow[i,q], Yrow[j,q]) = EF*(qx+qy) = u;  exp(-sqrt5*r)=exp2(-u)
//  CTX/CTY[pt*8+q] = packed bf16 {w*cos, w*sin}  (K=2 cosine dot, slots 20/21)
__global__ __launch_bounds__(640) void feat_kernel(
    const float* __restrict__ xin, const float* __restrict__ yin,
    const float* __restrict__ W1, const float* __restrict__ b1,
    const float* __restrict__ Ww, const float* __restrict__ bw,
    const float* __restrict__ Wf, const float* __restrict__ bf,
    const float* __restrict__ Ws, const float* __restrict__ bs,
    ushort* __restrict__ AXH, ushort* __restrict__ AXL,
    ushort* __restrict__ BYH, ushort* __restrict__ BYL,
    uint* __restrict__ CTX, uint* __restrict__ CTY)
{
    __shared__ float hsh[8][LATD + 4];
    __shared__ float raw[8][80];
    const int t = threadIdx.x;

    // phase 1: hidden layer
    if (t < 512) {
        const int pl = t & 7, l = t >> 3;
        const int g = blockIdx.x * 8 + pl;
        const bool isx = (g < NPTS);
        const float* pts = isx ? (xin + 3 * g) : (yin + 3 * (g - NPTS));
        const float z = fmaf(W1[l * 3 + 0], pts[0],
                        fmaf(W1[l * 3 + 1], pts[1],
                        fmaf(W1[l * 3 + 2], pts[2], b1[l])));
        hsh[pl][l] = selu_f(z);
    }
    __syncthreads();

    // phase 2: head dots
    {
        const int o  = t >> 3;
        const int pl = t & 7;
        const int q  = o / 10;
        const int e  = o % 10;
        const float* row;
        float acc;
        if (e == 0)      { row = Ww + q * LATD;                 acc = bw[q]; }
        else if (e <= 3) { row = Wf + (q * 3 + (e - 1)) * LATD; acc = bf[q * 3 + (e - 1)]; }
        else             { row = Ws + (q * 6 + (e - 4)) * LATD; acc = bs[q * 6 + (e - 4)]; }
#pragma unroll
        for (int l4 = 0; l4 < LATD / 4; ++l4) {
            const float4 rv = reinterpret_cast<const float4*>(row)[l4];
            const float4 hv = *reinterpret_cast<const float4*>(&hsh[pl][l4 * 4]);
            acc = fmaf(rv.x, hv.x, acc);
            acc = fmaf(rv.y, hv.y, acc);
            acc = fmaf(rv.z, hv.z, acc);
            acc = fmaf(rv.w, hv.w, acc);
        }
        raw[pl][o] = softplus_f(acc);
    }
    __syncthreads();

    // phase 3: expand quadratic form and emit split-bf16 rows
    if (t < 64) {
        const int pl2 = t >> 3, q2 = t & 7;
        const int g2  = blockIdx.x * 8 + pl2;
        const bool isx2 = (g2 < NPTS);
        const float* pts2 = isx2 ? (xin + 3 * g2) : (yin + 3 * (g2 - NPTS));
        const float c0 = pts2[0], c1 = pts2[1], c2 = pts2[2];
        const float* rr = raw[pl2] + q2 * 10;
        const float w  = rr[0];
        const float f0 = rr[1], f1 = rr[2], f2 = rr[3];
        const float s0 = rr[4], s1 = rr[5], s2 = rr[6];
        const float s3 = rr[7], s4 = rr[8], s5 = rr[9];

        // A = L L^T
        const float A00 = s0 * s0;
        const float A01 = s0 * s1;
        const float A02 = s0 * s3;
        const float A11 = fmaf(s1, s1, s2 * s2);
        const float A12 = fmaf(s1, s3, s2 * s4);
        const float A22 = fmaf(s3, s3, fmaf(s4, s4, s5 * s5));
        const float Ax0 = fmaf(A00, c0, fmaf(A01, c1, A02 * c2));
        const float Ax1 = fmaf(A01, c0, fmaf(A11, c1, A12 * c2));
        const float Ax2 = fmaf(A02, c0, fmaf(A12, c1, A22 * c2));
        const float pAp = fmaf(c0, Ax0, fmaf(c1, Ax1, c2 * Ax2));
        const float ph  = fmaf(f0, c0, fmaf(f1, c1, f2 * c2));
        float sn, cs;
        sincosf(6.283185307179586477f * ph, &sn, &cs);

        const float EF = 3.2259751249059600974f;   // sqrt(5)*log2(e)
        const float cf[10] = { EF * A00, EF * A11, EF * A22,
                               2.0f * EF * A01, 2.0f * EF * A02, 2.0f * EF * A12,
                               -2.0f * EF * Ax0, -2.0f * EF * Ax1, -2.0f * EF * Ax2,
                               EF * pAp };
        const float pv[10] = { c0 * c0, c1 * c1, c2 * c2,
                               c0 * c1, c0 * c2, c1 * c2,
                               c0, c1, c2, 1.0f };
        float slots[20];
#pragma unroll
        for (int k = 0; k < 10; ++k) {
            slots[k]      = isx2 ? cf[k] : pv[k];
            slots[10 + k] = isx2 ? pv[k] : cf[k];
        }
        ushort H[32], L[32];
#pragma unroll
        for (int k = 0; k < 32; ++k) { H[k] = 0; L[k] = 0; }
#pragma unroll
        for (int k = 0; k < 20; ++k) split_bf16(slots[k], H[k], L[k]);

        const int pi = isx2 ? g2 : (g2 - NPTS);
        ushort* dh = (isx2 ? AXH : BYH) + ((size_t)pi * 8 + q2) * 32;
        ushort* dl = (isx2 ? AXL : BYL) + ((size_t)pi * 8 + q2) * 32;
#pragma unroll
        for (int m = 0; m < 16; ++m) {
            ((uint*)dh)[m] = (uint)H[2 * m] | ((uint)H[2 * m + 1] << 16);
            ((uint*)dl)[m] = (uint)L[2 * m] | ((uint)L[2 * m + 1] << 16);
        }
        uint* ct = isx2 ? CTX : CTY;
        ct[(size_t)pi * 8 + q2] = (uint)bfrn(w * cs) | ((uint)bfrn(w * sn) << 16);
    }
}

// Pair kernel: wave = one 16x16 output tile (j-tile fixed per wave, i-tiles
// looped). u via 3 split-bf16 MFMAs, ct via 1 K=2 MFMA; epilogue does
// poly*exp2(-u)*ct per element. A-tiles staged in XOR-swizzled LDS.
// Register budget: Bh/Bl 64 + cvY 8 + acc/temps ~40 => fits the 170-VGPR cap
// of __launch_bounds__(256,3) with NO scratch spills (r10's 127MB FETCH bug).
__global__ __launch_bounds__(256, 3) void pair_kernel(
    const ushort* __restrict__ AXH, const ushort* __restrict__ AXL,
    const uint*  __restrict__ CTX,
    const ushort* __restrict__ BYH, const ushort* __restrict__ BYL,
    const uint*  __restrict__ CTY, float* __restrict__ out)
{
    __shared__ ushort sAH[16 * 256];   // 8 KB (swizzled)
    __shared__ ushort sAL[16 * 256];   // 8 KB (swizzled)
    __shared__ uint   sCT[16 * 9];     // stride-9 padded
    const int t   = threadIdx.x;
    const int wv  = t >> 6, ln = t & 63;
    const int col = ln & 15, kb = ln >> 4;
    const int j0  = blockIdx.x * 64 + wv * 16;
    const int it0 = blockIdx.y * NIT;

    // resident B-side fragments (j-tile fixed for the whole block)
    short8 Bh[8], Bl[8];
    uint   cvY[8];
    {
        const ushort* bh = BYH + (size_t)(j0 + col) * 256 + kb * 8;
        const ushort* bl = BYL + (size_t)(j0 + col) * 256 + kb * 8;
#pragma unroll
        for (int q = 0; q < 8; ++q) {
            Bh[q] = *reinterpret_cast<const short8*>(bh + q * 32);
            Bl[q] = *reinterpret_cast<const short8*>(bl + q * 32);
            cvY[q] = (kb == 2) ? CTY[(size_t)(j0 + col) * 8 + q] : 0u;
        }
    }
    const float P1 = 0.69314718055994530942f;   // ln2
    const float P2 = 0.16013630893549922444f;   // ln2^2/3

    for (int it = 0; it < NIT; ++it) {
        const int i0 = (it0 + it) * 16;
        if (it) __syncthreads();    // prior tile's reads done before overwrite
        {
            const uint4* srcH = reinterpret_cast<const uint4*>(AXH + (size_t)i0 * 256);
            const uint4* srcL = reinterpret_cast<const uint4*>(AXL + (size_t)i0 * 256);
#pragma unroll
            for (int u = 0; u < 2; ++u) {
                const int s   = t + u * 256;            // 0..511 16B-chunks
                const int row = s >> 5, sl = s & 31;
                const int ds  = row * 32 + (sl ^ row);  // XOR swizzle
                reinterpret_cast<uint4*>(sAH)[ds] = srcH[s];
                reinterpret_cast<uint4*>(sAL)[ds] = srcL[s];
            }
            if (t < 128) sCT[(t >> 3) * 9 + (t & 7)] =
                CTX[(size_t)(i0 + (t >> 3)) * 8 + (t & 7)];
        }
        __syncthreads();

        f32x4 kacc = {0.f, 0.f, 0.f, 0.f};
#pragma unroll
        for (int q = 0; q < 8; ++q) {
            // swizzled read: logical 16B-chunk (q*4+kb) of row col
            const int ro = col * 256 + (((q * 4 + kb) ^ col) << 3);
            const short8 Ah = *reinterpret_cast<const short8*>(sAH + ro);
            const short8 Al = *reinterpret_cast<const short8*>(sAL + ro);
            const f32x4 z = {0.f, 0.f, 0.f, 0.f};
            f32x4 au = __builtin_amdgcn_mfma_f32_16x16x32_bf16(Ah, Bh[q], z, 0, 0, 0);
            au = __builtin_amdgcn_mfma_f32_16x16x32_bf16(Al, Bh[q], au, 0, 0, 0);
            au = __builtin_amdgcn_mfma_f32_16x16x32_bf16(Ah, Bl[q], au, 0, 0, 0);
            const uint av = (kb == 2) ? sCT[col * 9 + q] : 0u;
            const f32x4 ac = __builtin_amdgcn_mfma_f32_16x16x32_bf16(
                ct_frag(av), ct_frag(cvY[q]), z, 0, 0, 0);
#pragma unroll
            for (int e = 0; e < 4; ++e) {
                const float u  = au[e];
                const float po = fmaf(u, fmaf(u, P2, P1), 1.0f);
                const float ex = __builtin_amdgcn_exp2f(-u);
                kacc[e] = fmaf(po * ex, ac[e], kacc[e]);
            }
        }
        // D layout: row = kb*4+e, col = lane&15  [m89-verified]
#pragma unroll
        for (int e = 0; e < 4; ++e)
            out[(size_t)(i0 + kb * 4 + e) * NPTS + j0 + col] = kacc[e];
    }
}

extern "C" void kernel_launch(void* const* d_in, const int* in_sizes, int n_in,
                              void* d_out, int out_size, void* d_ws, size_t ws_size,
                              hipStream_t stream) {
    const float* x  = (const float*)d_in[0];
    const float* y  = (const float*)d_in[1];
    const float* W1 = (const float*)d_in[2];
    const float* b1 = (const float*)d_in[3];
    const float* Ww = (const float*)d_in[4];
    const float* bw = (const float*)d_in[5];
    const float* Wf = (const float*)d_in[6];
    const float* bf = (const float*)d_in[7];
    const float* Ws = (const float*)d_in[8];
    const float* bs = (const float*)d_in[9];
    float* out = (float*)d_out;

    ushort* AXH = (ushort*)d_ws;                 // [2048][8][32] bf16 hi
    ushort* AXL = AXH + (size_t)NPTS * 256;      // lo
    ushort* BYH = AXL + (size_t)NPTS * 256;
    ushort* BYL = BYH + (size_t)NPTS * 256;
    uint*   CTX = (uint*)(BYL + (size_t)NPTS * 256);  // [2048][8] packed {wc,ws}
    uint*   CTY = CTX + (size_t)NPTS * 8;

    feat_kernel<<<dim3((2 * NPTS) / 8), dim3(640), 0, stream>>>(
        x, y, W1, b1, Ww, bw, Wf, bf, Ws, bs, AXH, AXL, BYH, BYL, CTX, CTY);

    // (32 j-blocks of 64 cols, 32 i-strips of NIT*16 rows)
    pair_kernel<<<dim3(NPTS / 64, NPTS / (NIT * 16)), dim3(256), 0, stream>>>(
        AXH, AXL, CTX, BYH, BYL, CTY, out);
}